// Round 1
// baseline (1862.562 us; speedup 1.0000x reference)
//
#include <hip/hip_runtime.h>
#include <math.h>

#define BATCH 16384
#define NF 128
#define HID 64
#define WAVES_PER_BLOCK 4

__device__ __forceinline__ float gelu_exact(float v) {
    // exact GELU: 0.5*v*(1+erf(v/sqrt(2)))
    return 0.5f * v * (1.0f + erff(v * 0.7071067811865475f));
}

__global__ __launch_bounds__(256, 4) void task_mlp_kernel(
    const float* __restrict__ x,
    const int* __restrict__ task_ids,
    const float* __restrict__ l1_emb,
    const float* __restrict__ l1_bias,
    const float* __restrict__ l2_emb,
    const float* __restrict__ l2_bias,
    float* __restrict__ out)
{
    __shared__ float xs[WAVES_PER_BLOCK][NF];

    const int wave = threadIdx.x >> 6;       // 0..3
    const int lane = threadIdx.x & 63;       // 0..63
    const int sample = blockIdx.x * WAVES_PER_BLOCK + wave;   // grid = BATCH/4 exactly

    // Stage this wave's x row into LDS (coalesced float2 per lane: 64*8B = 512B)
    const float2 xv2 = ((const float2*)(x + (size_t)sample * NF))[lane];
    xs[wave][lane * 2]     = xv2.x;
    xs[wave][lane * 2 + 1] = xv2.y;
    __syncthreads();

    const int task = task_ids[sample];

    // w1 gather: flat layout [f][h], f<128, h<64. Lane i, iter t reads float4
    // at float offset t*256 + i*4  ->  f = t*4 + (i>>4), h = (i&15)*4 .. +3
    const float4* w1 = (const float4*)(l1_emb + (size_t)task * (NF * HID));
    const int q  = lane & 15;   // h-quad index
    const int fo = lane >> 4;   // f offset within group of 4 rows

    float acc0 = 0.f, acc1 = 0.f, acc2 = 0.f, acc3 = 0.f;
    #pragma unroll 8
    for (int t = 0; t < 32; ++t) {
        const float4 w = w1[t * 64 + lane];          // 16B/lane, 1KiB/wave contiguous
        const float xv = xs[wave][t * 4 + fo];       // broadcast within 16-lane groups
        acc0 = fmaf(xv, w.x, acc0);
        acc1 = fmaf(xv, w.y, acc1);
        acc2 = fmaf(xv, w.z, acc2);
        acc3 = fmaf(xv, w.w, acc3);
    }

    // Reduce over the 4 f-offset groups (lanes i, i^16, i^32, i^48 share q)
    acc0 += __shfl_xor(acc0, 16); acc0 += __shfl_xor(acc0, 32);
    acc1 += __shfl_xor(acc1, 16); acc1 += __shfl_xor(acc1, 32);
    acc2 += __shfl_xor(acc2, 16); acc2 += __shfl_xor(acc2, 32);
    acc3 += __shfl_xor(acc3, 16); acc3 += __shfl_xor(acc3, 32);

    // Bias + exact GELU + dot with w2 (all 4 fo-groups do this redundantly; cache hits)
    const float4 b1 = ((const float4*)(l1_bias + (size_t)task * HID))[q];
    const float4 w2 = ((const float4*)(l2_emb + (size_t)task * HID))[q];

    float s = gelu_exact(acc0 + b1.x) * w2.x
            + gelu_exact(acc1 + b1.y) * w2.y
            + gelu_exact(acc2 + b1.z) * w2.z
            + gelu_exact(acc3 + b1.w) * w2.w;

    // Reduce over the 16 q-lanes within each 16-lane group
    s += __shfl_xor(s, 1);
    s += __shfl_xor(s, 2);
    s += __shfl_xor(s, 4);
    s += __shfl_xor(s, 8);

    if (lane == 0) {
        out[sample] = s + l2_bias[task];
    }
}

extern "C" void kernel_launch(void* const* d_in, const int* in_sizes, int n_in,
                              void* d_out, int out_size, void* d_ws, size_t ws_size,
                              hipStream_t stream) {
    const float* x        = (const float*)d_in[0];
    const int*   task_ids = (const int*)d_in[1];
    const float* l1_emb   = (const float*)d_in[2];
    const float* l1_bias  = (const float*)d_in[3];
    const float* l2_emb   = (const float*)d_in[4];
    const float* l2_bias  = (const float*)d_in[5];
    float* out = (float*)d_out;

    dim3 grid(BATCH / WAVES_PER_BLOCK);   // 4096 blocks
    dim3 block(64 * WAVES_PER_BLOCK);     // 256 threads = 4 waves
    task_mlp_kernel<<<grid, block, 0, stream>>>(x, task_ids, l1_emb, l1_bias,
                                                l2_emb, l2_bias, out);
}